// Round 1
// baseline (281.281 us; speedup 1.0000x reference)
//
#include <hip/hip_runtime.h>
#include <math.h>

#define HIDDEN   128
#define NCLS     8
#define NSCHEMES 5
#define KNEI     16

// W1t[j][i] = W1[i][j] : make per-hidden-unit weight rows contiguous so the
// wave-uniform reads in mlp_probs merge into s_load_dwordxN.
__global__ void transpose_w1(const float* __restrict__ W1, float* __restrict__ W1t) {
    int j = blockIdx.x;
    int i = threadIdx.x;
    W1t[j * HIDDEN + i] = W1[i * HIDDEN + j];
}

// One thread per node: probs[n] = softmax(relu(x@W1+b1)@W2+b2).
// x[128] lives in VGPRs (constant-indexed via full unroll). Weight loads are
// wave-uniform -> scalar (SMEM) loads; VALU does only the FMAs.
__global__ __launch_bounds__(64) void mlp_probs(
    const float* __restrict__ feats, const float* __restrict__ W1t,
    const float* __restrict__ b1, const float* __restrict__ W2,
    const float* __restrict__ b2, float* __restrict__ probs, int N)
{
    int n = blockIdx.x * 64 + threadIdx.x;
    bool active = (n < N);
    int nn = active ? n : (N - 1);

    float x[HIDDEN];
    const float4* xr = (const float4*)(feats + (size_t)nn * HIDDEN);
    #pragma unroll
    for (int i = 0; i < HIDDEN / 4; ++i) {
        float4 v = xr[i];
        x[4 * i + 0] = v.x; x[4 * i + 1] = v.y;
        x[4 * i + 2] = v.z; x[4 * i + 3] = v.w;
    }

    float o[NCLS];
    #pragma unroll
    for (int c = 0; c < NCLS; ++c) o[c] = b2[c];

    for (int j = 0; j < HIDDEN; ++j) {
        const float4* w4 = (const float4*)(W1t + j * HIDDEN);
        // 4 independent accumulators: break the 128-long dependent FMA chain.
        float a0 = 0.f, a1 = 0.f, a2 = 0.f, a3 = 0.f;
        #pragma unroll
        for (int i4 = 0; i4 < HIDDEN / 4; ++i4) {
            float4 w = w4[i4];
            a0 = fmaf(x[4 * i4 + 0], w.x, a0);
            a1 = fmaf(x[4 * i4 + 1], w.y, a1);
            a2 = fmaf(x[4 * i4 + 2], w.z, a2);
            a3 = fmaf(x[4 * i4 + 3], w.w, a3);
        }
        float h = (a0 + a1) + (a2 + a3) + b1[j];
        h = fmaxf(h, 0.f);
        const float* w2 = W2 + j * NCLS;
        #pragma unroll
        for (int c = 0; c < NCLS; ++c) o[c] = fmaf(h, w2[c], o[c]);
    }

    // softmax over 8 classes
    float m = o[0];
    #pragma unroll
    for (int c = 1; c < NCLS; ++c) m = fmaxf(m, o[c]);
    float s = 0.f;
    #pragma unroll
    for (int c = 0; c < NCLS; ++c) { o[c] = __expf(o[c] - m); s += o[c]; }
    float inv = 1.f / s;

    if (active) {
        float4* op = (float4*)(probs + (size_t)n * NCLS);
        op[0] = make_float4(o[0] * inv, o[1] * inv, o[2] * inv, o[3] * inv);
        op[1] = make_float4(o[4] * inv, o[5] * inv, o[6] * inv, o[7] * inv);
    }
}

// One thread per node: gather 5x16 neighbor prob rows (table is L2-resident),
// per-scheme mean, attention-softmax weighting, sigmoid gate with self probs.
__global__ __launch_bounds__(256) void combine(
    const int* __restrict__ nei, const float* __restrict__ probs,
    const float* __restrict__ attention, const float* __restrict__ alpha,
    float* __restrict__ out, int N)
{
    int n = blockIdx.x * 256 + threadIdx.x;
    if (n >= N) return;

    // softmax over schemes
    float aw[NSCHEMES];
    float m = -1e30f;
    #pragma unroll
    for (int s2 = 0; s2 < NSCHEMES; ++s2) {
        aw[s2] = attention[(size_t)n * NSCHEMES + s2];
        m = fmaxf(m, aw[s2]);
    }
    float ssum = 0.f;
    #pragma unroll
    for (int s2 = 0; s2 < NSCHEMES; ++s2) { aw[s2] = __expf(aw[s2] - m); ssum += aw[s2]; }
    float invs = 1.f / ssum;

    float acc[NCLS];
    #pragma unroll
    for (int c = 0; c < NCLS; ++c) acc[c] = 0.f;

    #pragma unroll
    for (int s2 = 0; s2 < NSCHEMES; ++s2) {
        const int* ip = nei + ((size_t)s2 * N + n) * KNEI;
        int4 idx[KNEI / 4];
        #pragma unroll
        for (int q = 0; q < KNEI / 4; ++q) idx[q] = ((const int4*)ip)[q];

        float sc[NCLS];
        #pragma unroll
        for (int c = 0; c < NCLS; ++c) sc[c] = 0.f;

        #pragma unroll
        for (int q = 0; q < KNEI / 4; ++q) {
            int ids[4] = {idx[q].x, idx[q].y, idx[q].z, idx[q].w};
            #pragma unroll
            for (int t = 0; t < 4; ++t) {
                const float4* pp = (const float4*)(probs + (size_t)ids[t] * NCLS);
                float4 p0 = pp[0], p1 = pp[1];
                sc[0] += p0.x; sc[1] += p0.y; sc[2] += p0.z; sc[3] += p0.w;
                sc[4] += p1.x; sc[5] += p1.y; sc[6] += p1.z; sc[7] += p1.w;
            }
        }
        float wgt = aw[s2] * invs * (1.f / (float)KNEI);
        #pragma unroll
        for (int c = 0; c < NCLS; ++c) acc[c] = fmaf(wgt, sc[c], acc[c]);
    }

    float g = 1.f / (1.f + __expf(-alpha[n]));
    const float4* sp = (const float4*)(probs + (size_t)n * NCLS);
    float4 s0 = sp[0], s1 = sp[1];
    float self[NCLS] = {s0.x, s0.y, s0.z, s0.w, s1.x, s1.y, s1.z, s1.w};

    float r[NCLS];
    #pragma unroll
    for (int c = 0; c < NCLS; ++c) r[c] = g * self[c] + (1.f - g) * acc[c];
    float4* op = (float4*)(out + (size_t)n * NCLS);
    op[0] = make_float4(r[0], r[1], r[2], r[3]);
    op[1] = make_float4(r[4], r[5], r[6], r[7]);
}

extern "C" void kernel_launch(void* const* d_in, const int* in_sizes, int n_in,
                              void* d_out, int out_size, void* d_ws, size_t ws_size,
                              hipStream_t stream) {
    const int*   sc_nei    = (const int*)d_in[0];
    const float* feats     = (const float*)d_in[1];
    const float* W1        = (const float*)d_in[2];
    const float* b1        = (const float*)d_in[3];
    const float* W2        = (const float*)d_in[4];
    const float* b2        = (const float*)d_in[5];
    const float* alpha     = (const float*)d_in[6];
    const float* attention = (const float*)d_in[7];
    float* out = (float*)d_out;

    int N = in_sizes[1] / HIDDEN;  // 50000 nodes

    float* W1t   = (float*)d_ws;                   // 128*128 floats = 64 KB
    float* probs = (float*)d_ws + HIDDEN * HIDDEN; // N*8 floats = 1.6 MB

    transpose_w1<<<HIDDEN, HIDDEN, 0, stream>>>(W1, W1t);
    mlp_probs<<<(N + 63) / 64, 64, 0, stream>>>(feats, W1t, b1, W2, b2, probs, N);
    combine<<<(N + 255) / 256, 256, 0, stream>>>(sc_nei, probs, attention, alpha, out, N);
}

// Round 2
// 144.901 us; speedup vs baseline: 1.9412x; 1.9412x over previous
//
#include <hip/hip_runtime.h>
#include <math.h>

#define HIDDEN   128
#define NCLS     8
#define NSCHEMES 5
#define KNEI     16

#define MT  64    // nodes per block
#define KC  32    // W1 k-chunk rows staged per barrier
#define AS  132   // A/H LDS row stride (floats): mult of 4 (b128 align), non-mult-8 spread
#define WS  136   // W1 chunk LDS row stride: 8*j0 starts hit banks {0,8,16,24} -> conflict-free

// Fused MLP+softmax as an LDS-tiled fp32 GEMM.
// Block: 256 threads / 64 nodes. Thread tile: 4 nodes (stride 16) x 8 hidden.
__global__ __launch_bounds__(256) void mlp_probs(
    const float* __restrict__ feats, const float* __restrict__ W1,
    const float* __restrict__ b1, const float* __restrict__ W2,
    const float* __restrict__ b2, float* __restrict__ probs, int N)
{
    __shared__ float Alds[MT * AS];          // 33792 B: feats tile, reused as H
    __shared__ float Wc[KC * WS];            // 17408 B: W1 k-chunk; reused as Opart
    __shared__ float W2lds[HIDDEN * NCLS];   // 4096 B
    __shared__ float b1lds[HIDDEN];
    __shared__ float b2lds[NCLS];

    const int tid = threadIdx.x;
    const int nodeBase = blockIdx.x * MT;

    // ---- stage W2 / b1 / b2 / feats tile
    {
        float4 v = ((const float4*)W2)[tid];  // 256 float4 == whole W2
        *(float4*)&W2lds[4 * tid] = v;
    }
    if (tid < HIDDEN) b1lds[tid] = b1[tid];
    if (tid < NCLS)   b2lds[tid] = b2[tid];

    #pragma unroll
    for (int idx = tid; idx < MT * HIDDEN / 4; idx += 256) {
        int r = idx >> 5, c4 = idx & 31;
        int n = nodeBase + r; if (n >= N) n = N - 1;
        float4 v = ((const float4*)(feats + (size_t)n * HIDDEN))[c4];
        *(float4*)&Alds[r * AS + 4 * c4] = v;
    }
    __syncthreads();

    // ---- phase 1: h = relu(A @ W1 + b1), K-chunked W1 staging
    const int n0 = tid & 15;    // node lane: rows n0 + 16*r
    const int j0 = tid >> 4;    // hidden group: cols 8*j0 .. 8*j0+7

    float acc[4][8];
    #pragma unroll
    for (int r = 0; r < 4; ++r)
        #pragma unroll
        for (int j = 0; j < 8; ++j) acc[r][j] = 0.f;

    for (int kc = 0; kc < HIDDEN; kc += KC) {
        // stage W1 rows [kc, kc+KC) in native [i][j] layout
        #pragma unroll
        for (int idx = tid; idx < KC * HIDDEN / 4; idx += 256) {
            int i = idx >> 5, c4 = idx & 31;
            float4 v = ((const float4*)(W1 + (size_t)(kc + i) * HIDDEN))[c4];
            *(float4*)&Wc[i * WS + 4 * c4] = v;
        }
        __syncthreads();

        #pragma unroll
        for (int k = 0; k < KC; k += 4) {
            float4 a[4];
            #pragma unroll
            for (int r = 0; r < 4; ++r)
                a[r] = *(const float4*)&Alds[(n0 + 16 * r) * AS + kc + k];
            float4 w[4][2];
            #pragma unroll
            for (int kk = 0; kk < 4; ++kk) {
                w[kk][0] = *(const float4*)&Wc[(k + kk) * WS + 8 * j0];
                w[kk][1] = *(const float4*)&Wc[(k + kk) * WS + 8 * j0 + 4];
            }
            #pragma unroll
            for (int r = 0; r < 4; ++r) {
                float av[4] = {a[r].x, a[r].y, a[r].z, a[r].w};
                #pragma unroll
                for (int kk = 0; kk < 4; ++kk) {
                    acc[r][0] = fmaf(av[kk], w[kk][0].x, acc[r][0]);
                    acc[r][1] = fmaf(av[kk], w[kk][0].y, acc[r][1]);
                    acc[r][2] = fmaf(av[kk], w[kk][0].z, acc[r][2]);
                    acc[r][3] = fmaf(av[kk], w[kk][0].w, acc[r][3]);
                    acc[r][4] = fmaf(av[kk], w[kk][1].x, acc[r][4]);
                    acc[r][5] = fmaf(av[kk], w[kk][1].y, acc[r][5]);
                    acc[r][6] = fmaf(av[kk], w[kk][1].z, acc[r][6]);
                    acc[r][7] = fmaf(av[kk], w[kk][1].w, acc[r][7]);
                }
            }
        }
        __syncthreads();   // all reads of Wc done before next-stage overwrite
    }

    // ---- relu + bias, write H into Alds (A reads are done: loop-exit barrier)
    #pragma unroll
    for (int r = 0; r < 4; ++r) {
        int row = n0 + 16 * r;
        float4 h0, h1;
        h0.x = fmaxf(acc[r][0] + b1lds[8 * j0 + 0], 0.f);
        h0.y = fmaxf(acc[r][1] + b1lds[8 * j0 + 1], 0.f);
        h0.z = fmaxf(acc[r][2] + b1lds[8 * j0 + 2], 0.f);
        h0.w = fmaxf(acc[r][3] + b1lds[8 * j0 + 3], 0.f);
        h1.x = fmaxf(acc[r][4] + b1lds[8 * j0 + 4], 0.f);
        h1.y = fmaxf(acc[r][5] + b1lds[8 * j0 + 5], 0.f);
        h1.z = fmaxf(acc[r][6] + b1lds[8 * j0 + 6], 0.f);
        h1.w = fmaxf(acc[r][7] + b1lds[8 * j0 + 7], 0.f);
        *(float4*)&Alds[row * AS + 8 * j0]     = h0;
        *(float4*)&Alds[row * AS + 8 * j0 + 4] = h1;
    }
    __syncthreads();

    // ---- phase 2: o = H @ W2 ; split j across 4 threads per node
    float (*Opart)[MT][9] = (float (*)[MT][9])Wc;  // overlay (Wc dead)
    {
        const int node = tid & 63;
        const int jr   = tid >> 6;   // 0..3 -> j in [32*jr, 32*jr+32)
        float o[NCLS];
        #pragma unroll
        for (int c = 0; c < NCLS; ++c) o[c] = 0.f;
        #pragma unroll
        for (int jj = 0; jj < 32; jj += 4) {
            int j = jr * 32 + jj;
            float4 h = *(const float4*)&Alds[node * AS + j];
            float hv[4] = {h.x, h.y, h.z, h.w};
            #pragma unroll
            for (int q = 0; q < 4; ++q) {
                float4 w0 = *(const float4*)&W2lds[(j + q) * NCLS];
                float4 w1 = *(const float4*)&W2lds[(j + q) * NCLS + 4];
                o[0] = fmaf(hv[q], w0.x, o[0]);
                o[1] = fmaf(hv[q], w0.y, o[1]);
                o[2] = fmaf(hv[q], w0.z, o[2]);
                o[3] = fmaf(hv[q], w0.w, o[3]);
                o[4] = fmaf(hv[q], w1.x, o[4]);
                o[5] = fmaf(hv[q], w1.y, o[5]);
                o[6] = fmaf(hv[q], w1.z, o[6]);
                o[7] = fmaf(hv[q], w1.w, o[7]);
            }
        }
        #pragma unroll
        for (int c = 0; c < NCLS; ++c) Opart[jr][node][c] = o[c];  // stride-9: conflict-free
    }
    __syncthreads();

    // ---- finalize: reduce 4 partials, + b2, softmax, write
    if (tid < MT) {
        int n = nodeBase + tid;
        if (n < N) {
            float o[NCLS];
            #pragma unroll
            for (int c = 0; c < NCLS; ++c)
                o[c] = b2lds[c] + Opart[0][tid][c] + Opart[1][tid][c]
                     + Opart[2][tid][c] + Opart[3][tid][c];
            float m = o[0];
            #pragma unroll
            for (int c = 1; c < NCLS; ++c) m = fmaxf(m, o[c]);
            float s = 0.f;
            #pragma unroll
            for (int c = 0; c < NCLS; ++c) { o[c] = __expf(o[c] - m); s += o[c]; }
            float inv = 1.f / s;
            float4* op = (float4*)(probs + (size_t)n * NCLS);
            op[0] = make_float4(o[0] * inv, o[1] * inv, o[2] * inv, o[3] * inv);
            op[1] = make_float4(o[4] * inv, o[5] * inv, o[6] * inv, o[7] * inv);
        }
    }
}

// One thread per (node, class): lanes c=0..7 of a node gather one contiguous
// 32 B chunk of the L2-resident prob table -> 8 transactions per wave-load.
__global__ __launch_bounds__(256) void combine(
    const int* __restrict__ nei, const float* __restrict__ probs,
    const float* __restrict__ attention, const float* __restrict__ alpha,
    float* __restrict__ out, int N)
{
    int t = blockIdx.x * 256 + threadIdx.x;
    int n = t >> 3;
    int c = t & 7;
    if (n >= N) return;

    // attention softmax over 5 schemes
    float aw[NSCHEMES];
    float m = -1e30f;
    #pragma unroll
    for (int s = 0; s < NSCHEMES; ++s) {
        aw[s] = attention[(size_t)n * NSCHEMES + s];
        m = fmaxf(m, aw[s]);
    }
    float ssum = 0.f;
    #pragma unroll
    for (int s = 0; s < NSCHEMES; ++s) { aw[s] = __expf(aw[s] - m); ssum += aw[s]; }
    float invs = 1.f / ssum;

    float acc = 0.f;
    #pragma unroll
    for (int s = 0; s < NSCHEMES; ++s) {
        const int* ip = nei + ((size_t)s * N + n) * KNEI;
        int4 q0 = ((const int4*)ip)[0];
        int4 q1 = ((const int4*)ip)[1];
        int4 q2 = ((const int4*)ip)[2];
        int4 q3 = ((const int4*)ip)[3];
        float p[KNEI];
        p[ 0] = probs[(size_t)q0.x * NCLS + c];
        p[ 1] = probs[(size_t)q0.y * NCLS + c];
        p[ 2] = probs[(size_t)q0.z * NCLS + c];
        p[ 3] = probs[(size_t)q0.w * NCLS + c];
        p[ 4] = probs[(size_t)q1.x * NCLS + c];
        p[ 5] = probs[(size_t)q1.y * NCLS + c];
        p[ 6] = probs[(size_t)q1.z * NCLS + c];
        p[ 7] = probs[(size_t)q1.w * NCLS + c];
        p[ 8] = probs[(size_t)q2.x * NCLS + c];
        p[ 9] = probs[(size_t)q2.y * NCLS + c];
        p[10] = probs[(size_t)q2.z * NCLS + c];
        p[11] = probs[(size_t)q2.w * NCLS + c];
        p[12] = probs[(size_t)q3.x * NCLS + c];
        p[13] = probs[(size_t)q3.y * NCLS + c];
        p[14] = probs[(size_t)q3.z * NCLS + c];
        p[15] = probs[(size_t)q3.w * NCLS + c];
        float sum = ((p[0] + p[1]) + (p[2] + p[3])) + ((p[4] + p[5]) + (p[6] + p[7]))
                  + ((p[8] + p[9]) + (p[10] + p[11])) + ((p[12] + p[13]) + (p[14] + p[15]));
        acc = fmaf(aw[s] * invs * (1.f / (float)KNEI), sum, acc);
    }

    float g = 1.f / (1.f + __expf(-alpha[n]));
    float self = probs[(size_t)n * NCLS + c];
    out[t] = g * self + (1.f - g) * acc;
}

extern "C" void kernel_launch(void* const* d_in, const int* in_sizes, int n_in,
                              void* d_out, int out_size, void* d_ws, size_t ws_size,
                              hipStream_t stream) {
    const int*   sc_nei    = (const int*)d_in[0];
    const float* feats     = (const float*)d_in[1];
    const float* W1        = (const float*)d_in[2];
    const float* b1        = (const float*)d_in[3];
    const float* W2        = (const float*)d_in[4];
    const float* b2        = (const float*)d_in[5];
    const float* alpha     = (const float*)d_in[6];
    const float* attention = (const float*)d_in[7];
    float* out = (float*)d_out;

    int N = in_sizes[1] / HIDDEN;  // 50000 nodes

    float* probs = (float*)d_ws;   // N*8 floats = 1.6 MB

    mlp_probs<<<(N + MT - 1) / MT, 256, 0, stream>>>(feats, W1, b1, W2, b2, probs, N);
    combine<<<((N * NCLS) + 255) / 256, 256, 0, stream>>>(sc_nei, probs, attention, alpha, out, N);
}

// Round 3
// 141.066 us; speedup vs baseline: 1.9940x; 1.0272x over previous
//
#include <hip/hip_runtime.h>
#include <math.h>

#define HIDDEN   128
#define NCLS     8
#define NSCHEMES 5
#define KNEI     16

#define MT   64    // nodes per block
#define KC   32    // k-chunk rows staged per barrier
#define ASTR 36    // A-chunk LDS row stride (floats): 4n0 mod 32 -> 2-way (free)
#define WSTR 136   // W-chunk LDS row stride: 8*(i+j0) mod 32 -> 4 disjoint bank groups

// Fused MLP+softmax, fp32 LDS-tiled GEMM, K-streamed A and W chunks.
// Block: 256 threads / 64 nodes. Thread tile: 4 nodes (stride 16) x 8 hidden.
// Phase 2 (H @ W2) runs from registers; 16-way j-reduction = shfl + small LDS.
__global__ __launch_bounds__(256) void mlp_probs(
    const float* __restrict__ feats, const float* __restrict__ W1,
    const float* __restrict__ b1, const float* __restrict__ W2,
    const float* __restrict__ b2, float* __restrict__ probs, int N)
{
    __shared__ float Ach[MT * ASTR];        // 9216 B  : A k-chunk [node][k]
    __shared__ float Wc[KC * WSTR];         // 17408 B : W1 k-chunk; overlaid as Red[4][64][12] later
    __shared__ float W2lds[HIDDEN * NCLS];  // 4096 B
    __shared__ float b1v[HIDDEN];
    __shared__ float b2v[NCLS];

    const int tid = threadIdx.x;
    const int nodeBase = blockIdx.x * MT;
    const int n0 = tid & 15;    // node lane: rows n0 + 16*r
    const int j0 = tid >> 4;    // hidden group: cols 8*j0 .. 8*j0+7

    // one-time stages (first chunk barrier fences these)
    {
        float4 v = ((const float4*)W2)[tid];   // 256 float4 == whole W2
        *(float4*)&W2lds[4 * tid] = v;
    }
    if (tid < HIDDEN) b1v[tid] = b1[tid];
    if (tid < NCLS)   b2v[tid] = b2[tid];

    float acc[4][8];
    #pragma unroll
    for (int r = 0; r < 4; ++r)
        #pragma unroll
        for (int j = 0; j < 8; ++j) acc[r][j] = 0.f;

    for (int kc = 0; kc < HIDDEN; kc += KC) {
        // stage A chunk: 64 nodes x 32 floats (512 float4, 2 per thread)
        #pragma unroll
        for (int idx = tid; idx < MT * KC / 4; idx += 256) {
            int r = idx >> 3, c4 = idx & 7;
            int n = nodeBase + r; if (n >= N) n = N - 1;
            float4 v = ((const float4*)(feats + (size_t)n * HIDDEN + kc))[c4];
            *(float4*)&Ach[r * ASTR + 4 * c4] = v;
        }
        // stage W1 chunk rows [kc, kc+KC) in native [i][j] layout
        #pragma unroll
        for (int idx = tid; idx < KC * HIDDEN / 4; idx += 256) {
            int i = idx >> 5, c4 = idx & 31;
            float4 v = ((const float4*)(W1 + (size_t)(kc + i) * HIDDEN))[c4];
            *(float4*)&Wc[i * WSTR + 4 * c4] = v;
        }
        __syncthreads();

        #pragma unroll
        for (int k = 0; k < KC; k += 4) {
            float4 a[4];
            #pragma unroll
            for (int r = 0; r < 4; ++r)
                a[r] = *(const float4*)&Ach[(n0 + 16 * r) * ASTR + k];
            float4 w[4][2];
            #pragma unroll
            for (int kk = 0; kk < 4; ++kk) {
                w[kk][0] = *(const float4*)&Wc[(k + kk) * WSTR + 8 * j0];
                w[kk][1] = *(const float4*)&Wc[(k + kk) * WSTR + 8 * j0 + 4];
            }
            #pragma unroll
            for (int r = 0; r < 4; ++r) {
                float av[4] = {a[r].x, a[r].y, a[r].z, a[r].w};
                #pragma unroll
                for (int kk = 0; kk < 4; ++kk) {
                    acc[r][0] = fmaf(av[kk], w[kk][0].x, acc[r][0]);
                    acc[r][1] = fmaf(av[kk], w[kk][0].y, acc[r][1]);
                    acc[r][2] = fmaf(av[kk], w[kk][0].z, acc[r][2]);
                    acc[r][3] = fmaf(av[kk], w[kk][0].w, acc[r][3]);
                    acc[r][4] = fmaf(av[kk], w[kk][1].x, acc[r][4]);
                    acc[r][5] = fmaf(av[kk], w[kk][1].y, acc[r][5]);
                    acc[r][6] = fmaf(av[kk], w[kk][1].z, acc[r][6]);
                    acc[r][7] = fmaf(av[kk], w[kk][1].w, acc[r][7]);
                }
            }
        }
        __syncthreads();   // Wc/Ach reads done before next-stage overwrite
    }

    // ---- h = relu(acc + b1) in registers
    {
        float4 bA = *(const float4*)&b1v[8 * j0];
        float4 bB = *(const float4*)&b1v[8 * j0 + 4];
        float bb[8] = {bA.x, bA.y, bA.z, bA.w, bB.x, bB.y, bB.z, bB.w};
        #pragma unroll
        for (int r = 0; r < 4; ++r)
            #pragma unroll
            for (int j = 0; j < 8; ++j)
                acc[r][j] = fmaxf(acc[r][j] + bb[j], 0.f);
    }

    // ---- phase 2: o_partial = h_local @ W2 (8 j's per thread), pure registers
    float o[4][NCLS];
    #pragma unroll
    for (int r = 0; r < 4; ++r)
        #pragma unroll
        for (int c = 0; c < NCLS; ++c) o[r][c] = 0.f;

    #pragma unroll
    for (int jj = 0; jj < 8; ++jj) {
        float4 w0 = *(const float4*)&W2lds[(8 * j0 + jj) * NCLS];
        float4 w1 = *(const float4*)&W2lds[(8 * j0 + jj) * NCLS + 4];
        #pragma unroll
        for (int r = 0; r < 4; ++r) {
            float h = acc[r][jj];
            o[r][0] = fmaf(h, w0.x, o[r][0]);
            o[r][1] = fmaf(h, w0.y, o[r][1]);
            o[r][2] = fmaf(h, w0.z, o[r][2]);
            o[r][3] = fmaf(h, w0.w, o[r][3]);
            o[r][4] = fmaf(h, w1.x, o[r][4]);
            o[r][5] = fmaf(h, w1.y, o[r][5]);
            o[r][6] = fmaf(h, w1.z, o[r][6]);
            o[r][7] = fmaf(h, w1.w, o[r][7]);
        }
    }

    // intra-wave reduce across the 4 j0-subgroups (lanes ^16, ^32)
    #pragma unroll
    for (int r = 0; r < 4; ++r)
        #pragma unroll
        for (int c = 0; c < NCLS; ++c) {
            float v = o[r][c];
            v += __shfl_xor(v, 16, 64);
            v += __shfl_xor(v, 32, 64);
            o[r][c] = v;
        }

    // cross-wave partials: overlay Red[wave][64][12] on dead Wc
    float* Red = Wc;
    const int wv = tid >> 6;
    if ((tid & 48) == 0) {     // one lane per (wave, n0)
        #pragma unroll
        for (int r = 0; r < 4; ++r) {
            int node = n0 + 16 * r;
            float* dst = &Red[(wv * MT + node) * 12];
            *(float4*)dst       = make_float4(o[r][0], o[r][1], o[r][2], o[r][3]);
            *(float4*)(dst + 4) = make_float4(o[r][4], o[r][5], o[r][6], o[r][7]);
        }
    }
    __syncthreads();

    // ---- finalize: sum 4 wave-partials, + b2, softmax, write
    if (tid < MT) {
        int n = nodeBase + tid;
        if (n < N) {
            float oo[NCLS];
            #pragma unroll
            for (int c = 0; c < NCLS; ++c) oo[c] = b2v[c];
            #pragma unroll
            for (int w = 0; w < 4; ++w) {
                float4 p0 = *(const float4*)&Red[(w * MT + tid) * 12];
                float4 p1 = *(const float4*)&Red[(w * MT + tid) * 12 + 4];
                oo[0] += p0.x; oo[1] += p0.y; oo[2] += p0.z; oo[3] += p0.w;
                oo[4] += p1.x; oo[5] += p1.y; oo[6] += p1.z; oo[7] += p1.w;
            }
            float m = oo[0];
            #pragma unroll
            for (int c = 1; c < NCLS; ++c) m = fmaxf(m, oo[c]);
            float s = 0.f;
            #pragma unroll
            for (int c = 0; c < NCLS; ++c) { oo[c] = __expf(oo[c] - m); s += oo[c]; }
            float inv = 1.f / s;
            float4* op = (float4*)(probs + (size_t)n * NCLS);
            op[0] = make_float4(oo[0] * inv, oo[1] * inv, oo[2] * inv, oo[3] * inv);
            op[1] = make_float4(oo[4] * inv, oo[5] * inv, oo[6] * inv, oo[7] * inv);
        }
    }
}

// One thread per (node, class): lanes c=0..7 of a node gather one contiguous
// 32 B chunk of the L2-resident prob table -> 8 transactions per wave-load.
__global__ __launch_bounds__(256) void combine(
    const int* __restrict__ nei, const float* __restrict__ probs,
    const float* __restrict__ attention, const float* __restrict__ alpha,
    float* __restrict__ out, int N)
{
    int t = blockIdx.x * 256 + threadIdx.x;
    int n = t >> 3;
    int c = t & 7;
    if (n >= N) return;

    float aw[NSCHEMES];
    float m = -1e30f;
    #pragma unroll
    for (int s = 0; s < NSCHEMES; ++s) {
        aw[s] = attention[(size_t)n * NSCHEMES + s];
        m = fmaxf(m, aw[s]);
    }
    float ssum = 0.f;
    #pragma unroll
    for (int s = 0; s < NSCHEMES; ++s) { aw[s] = __expf(aw[s] - m); ssum += aw[s]; }
    float invs = 1.f / ssum;

    float acc = 0.f;
    #pragma unroll
    for (int s = 0; s < NSCHEMES; ++s) {
        const int* ip = nei + ((size_t)s * N + n) * KNEI;
        int4 q0 = ((const int4*)ip)[0];
        int4 q1 = ((const int4*)ip)[1];
        int4 q2 = ((const int4*)ip)[2];
        int4 q3 = ((const int4*)ip)[3];
        float p[KNEI];
        p[ 0] = probs[(size_t)q0.x * NCLS + c];
        p[ 1] = probs[(size_t)q0.y * NCLS + c];
        p[ 2] = probs[(size_t)q0.z * NCLS + c];
        p[ 3] = probs[(size_t)q0.w * NCLS + c];
        p[ 4] = probs[(size_t)q1.x * NCLS + c];
        p[ 5] = probs[(size_t)q1.y * NCLS + c];
        p[ 6] = probs[(size_t)q1.z * NCLS + c];
        p[ 7] = probs[(size_t)q1.w * NCLS + c];
        p[ 8] = probs[(size_t)q2.x * NCLS + c];
        p[ 9] = probs[(size_t)q2.y * NCLS + c];
        p[10] = probs[(size_t)q2.z * NCLS + c];
        p[11] = probs[(size_t)q2.w * NCLS + c];
        p[12] = probs[(size_t)q3.x * NCLS + c];
        p[13] = probs[(size_t)q3.y * NCLS + c];
        p[14] = probs[(size_t)q3.z * NCLS + c];
        p[15] = probs[(size_t)q3.w * NCLS + c];
        float sum = ((p[0] + p[1]) + (p[2] + p[3])) + ((p[4] + p[5]) + (p[6] + p[7]))
                  + ((p[8] + p[9]) + (p[10] + p[11])) + ((p[12] + p[13]) + (p[14] + p[15]));
        acc = fmaf(aw[s] * invs * (1.f / (float)KNEI), sum, acc);
    }

    float g = 1.f / (1.f + __expf(-alpha[n]));
    float self = probs[(size_t)n * NCLS + c];
    out[t] = g * self + (1.f - g) * acc;
}

extern "C" void kernel_launch(void* const* d_in, const int* in_sizes, int n_in,
                              void* d_out, int out_size, void* d_ws, size_t ws_size,
                              hipStream_t stream) {
    const int*   sc_nei    = (const int*)d_in[0];
    const float* feats     = (const float*)d_in[1];
    const float* W1        = (const float*)d_in[2];
    const float* b1        = (const float*)d_in[3];
    const float* W2        = (const float*)d_in[4];
    const float* b2        = (const float*)d_in[5];
    const float* alpha     = (const float*)d_in[6];
    const float* attention = (const float*)d_in[7];
    float* out = (float*)d_out;

    int N = in_sizes[1] / HIDDEN;  // 50000 nodes

    float* probs = (float*)d_ws;   // N*8 floats = 1.6 MB

    mlp_probs<<<(N + MT - 1) / MT, 256, 0, stream>>>(feats, W1, b1, W2, b2, probs, N);
    combine<<<((N * NCLS) + 255) / 256, 256, 0, stream>>>(sc_nei, probs, attention, alpha, out, N);
}

// Round 4
// 140.254 us; speedup vs baseline: 2.0055x; 1.0058x over previous
//
#include <hip/hip_runtime.h>
#include <math.h>

#define HIDDEN   128
#define NCLS     8
#define NSCHEMES 5
#define KNEI     16

#define MT   32    // nodes per block
#define KC   32    // k-chunk rows staged per barrier
#define ASTR 36    // A-chunk LDS row stride: 4*n0 mod 32 -> 2-way alias (free per m136)
#define WSTR 136   // W-chunk LDS row stride: 8*j0 starts hit banks {0,8,16,24} -> conflict-free

// Fused MLP+softmax, fp32 LDS-tiled GEMM, K-streamed A and W chunks.
// Block: 256 threads / 32 nodes. Thread tile: 2 nodes (stride 16) x 8 hidden.
// __launch_bounds__(256,4): pin VGPR<=128 so 4 waves/SIMD actually materialize.
__global__ __launch_bounds__(256, 4) void mlp_probs(
    const float* __restrict__ feats, const float* __restrict__ W1,
    const float* __restrict__ b1, const float* __restrict__ W2,
    const float* __restrict__ b2, float* __restrict__ probs, int N)
{
    __shared__ float Ach[MT * ASTR];        // 4608 B  : A k-chunk [node][k]
    __shared__ float Wc[KC * WSTR];         // 17408 B : W1 k-chunk; overlaid as Red[4][32][12]
    __shared__ float W2lds[HIDDEN * NCLS];  // 4096 B
    __shared__ float b1v[HIDDEN];
    __shared__ float b2v[NCLS];

    const int tid = threadIdx.x;
    const int nodeBase = blockIdx.x * MT;
    const int n0 = tid & 15;    // node lane: rows n0, n0+16
    const int j0 = tid >> 4;    // hidden group: cols 8*j0 .. 8*j0+7

    {
        float4 v = ((const float4*)W2)[tid];   // 256 float4 == whole W2
        *(float4*)&W2lds[4 * tid] = v;
    }
    if (tid < HIDDEN) b1v[tid] = b1[tid];
    if (tid < NCLS)   b2v[tid] = b2[tid];

    float acc[2][8];
    #pragma unroll
    for (int r = 0; r < 2; ++r)
        #pragma unroll
        for (int j = 0; j < 8; ++j) acc[r][j] = 0.f;

    for (int kc = 0; kc < HIDDEN; kc += KC) {
        // stage A chunk: 32 nodes x 32 floats = 256 float4, 1 per thread
        {
            int r = tid >> 3, c4 = tid & 7;
            int n = nodeBase + r; if (n >= N) n = N - 1;
            float4 v = ((const float4*)(feats + (size_t)n * HIDDEN + kc))[c4];
            *(float4*)&Ach[r * ASTR + 4 * c4] = v;
        }
        // stage W1 chunk rows [kc, kc+KC): 1024 float4, 4 per thread
        #pragma unroll
        for (int idx = tid; idx < KC * HIDDEN / 4; idx += 256) {
            int i = idx >> 5, c4 = idx & 31;
            float4 v = ((const float4*)(W1 + (size_t)(kc + i) * HIDDEN))[c4];
            *(float4*)&Wc[i * WSTR + 4 * c4] = v;
        }
        __syncthreads();

        #pragma unroll
        for (int k = 0; k < KC; k += 4) {
            float4 a[2];
            #pragma unroll
            for (int r = 0; r < 2; ++r)
                a[r] = *(const float4*)&Ach[(n0 + 16 * r) * ASTR + k];
            float4 w[4][2];
            #pragma unroll
            for (int kk = 0; kk < 4; ++kk) {
                w[kk][0] = *(const float4*)&Wc[(k + kk) * WSTR + 8 * j0];
                w[kk][1] = *(const float4*)&Wc[(k + kk) * WSTR + 8 * j0 + 4];
            }
            #pragma unroll
            for (int r = 0; r < 2; ++r) {
                float av[4] = {a[r].x, a[r].y, a[r].z, a[r].w};
                #pragma unroll
                for (int kk = 0; kk < 4; ++kk) {
                    acc[r][0] = fmaf(av[kk], w[kk][0].x, acc[r][0]);
                    acc[r][1] = fmaf(av[kk], w[kk][0].y, acc[r][1]);
                    acc[r][2] = fmaf(av[kk], w[kk][0].z, acc[r][2]);
                    acc[r][3] = fmaf(av[kk], w[kk][0].w, acc[r][3]);
                    acc[r][4] = fmaf(av[kk], w[kk][1].x, acc[r][4]);
                    acc[r][5] = fmaf(av[kk], w[kk][1].y, acc[r][5]);
                    acc[r][6] = fmaf(av[kk], w[kk][1].z, acc[r][6]);
                    acc[r][7] = fmaf(av[kk], w[kk][1].w, acc[r][7]);
                }
            }
        }
        __syncthreads();   // Ach/Wc reads done before next-stage overwrite
    }

    // ---- h = relu(acc + b1) in registers
    {
        float4 bA = *(const float4*)&b1v[8 * j0];
        float4 bB = *(const float4*)&b1v[8 * j0 + 4];
        float bb[8] = {bA.x, bA.y, bA.z, bA.w, bB.x, bB.y, bB.z, bB.w};
        #pragma unroll
        for (int r = 0; r < 2; ++r)
            #pragma unroll
            for (int j = 0; j < 8; ++j)
                acc[r][j] = fmaxf(acc[r][j] + bb[j], 0.f);
    }

    // ---- phase 2: per node-row, o = h_local @ W2 with a single o[8] live
    float* Red = Wc;           // overlay on dead Wc: Red[wave][MT][12]
    const int wv = tid >> 6;
    #pragma unroll
    for (int r = 0; r < 2; ++r) {
        float o[NCLS];
        #pragma unroll
        for (int c = 0; c < NCLS; ++c) o[c] = 0.f;
        #pragma unroll
        for (int jj = 0; jj < 8; ++jj) {
            float4 w0 = *(const float4*)&W2lds[(8 * j0 + jj) * NCLS];
            float4 w1 = *(const float4*)&W2lds[(8 * j0 + jj) * NCLS + 4];
            float h = acc[r][jj];
            o[0] = fmaf(h, w0.x, o[0]);
            o[1] = fmaf(h, w0.y, o[1]);
            o[2] = fmaf(h, w0.z, o[2]);
            o[3] = fmaf(h, w0.w, o[3]);
            o[4] = fmaf(h, w1.x, o[4]);
            o[5] = fmaf(h, w1.y, o[5]);
            o[6] = fmaf(h, w1.z, o[6]);
            o[7] = fmaf(h, w1.w, o[7]);
        }
        // reduce across the 4 j0-subgroups of this wave (lanes ^16, ^32)
        #pragma unroll
        for (int c = 0; c < NCLS; ++c) {
            float v = o[c];
            v += __shfl_xor(v, 16, 64);
            v += __shfl_xor(v, 32, 64);
            o[c] = v;
        }
        if ((tid & 48) == 0) {   // one subgroup per wave holds the sum
            int node = n0 + 16 * r;
            float* dst = &Red[(wv * MT + node) * 12];
            *(float4*)dst       = make_float4(o[0], o[1], o[2], o[3]);
            *(float4*)(dst + 4) = make_float4(o[4], o[5], o[6], o[7]);
        }
    }
    __syncthreads();

    // ---- finalize: sum 4 wave-partials, + b2, softmax, write
    if (tid < MT) {
        int n = nodeBase + tid;
        if (n < N) {
            float oo[NCLS];
            #pragma unroll
            for (int c = 0; c < NCLS; ++c) oo[c] = b2v[c];
            #pragma unroll
            for (int w = 0; w < 4; ++w) {
                float4 p0 = *(const float4*)&Red[(w * MT + tid) * 12];
                float4 p1 = *(const float4*)&Red[(w * MT + tid) * 12 + 4];
                oo[0] += p0.x; oo[1] += p0.y; oo[2] += p0.z; oo[3] += p0.w;
                oo[4] += p1.x; oo[5] += p1.y; oo[6] += p1.z; oo[7] += p1.w;
            }
            float m = oo[0];
            #pragma unroll
            for (int c = 1; c < NCLS; ++c) m = fmaxf(m, oo[c]);
            float s = 0.f;
            #pragma unroll
            for (int c = 0; c < NCLS; ++c) { oo[c] = __expf(oo[c] - m); s += oo[c]; }
            float inv = 1.f / s;
            float4* op = (float4*)(probs + (size_t)n * NCLS);
            op[0] = make_float4(oo[0] * inv, oo[1] * inv, oo[2] * inv, oo[3] * inv);
            op[1] = make_float4(oo[4] * inv, oo[5] * inv, oo[6] * inv, oo[7] * inv);
        }
    }
}

// 8 lanes per node. Lane L owns neighbor rows (s, k) for k in {L, L+8}:
// 10 rows, each loaded as two float4 (the full 8-class prob vector), weighted
// accumulation in registers, then a 3-step shfl_xor butterfly over the 8-lane
// group; lane L emits class L. ~30 VMEM insts/wave vs ~100 before.
__global__ __launch_bounds__(256) void combine(
    const int* __restrict__ nei, const float* __restrict__ probs,
    const float* __restrict__ attention, const float* __restrict__ alpha,
    float* __restrict__ out, int N)
{
    int t = blockIdx.x * 256 + threadIdx.x;
    int n = t >> 3;
    int L = t & 7;
    if (n >= N) return;

    // attention softmax over 5 schemes
    float aw[NSCHEMES];
    float m = -1e30f;
    #pragma unroll
    for (int s = 0; s < NSCHEMES; ++s) {
        aw[s] = attention[(size_t)n * NSCHEMES + s];
        m = fmaxf(m, aw[s]);
    }
    float ssum = 0.f;
    #pragma unroll
    for (int s = 0; s < NSCHEMES; ++s) { aw[s] = __expf(aw[s] - m); ssum += aw[s]; }

    float g = 1.f / (1.f + __expf(-alpha[n]));
    float scale = (1.f - g) / (ssum * (float)KNEI);
    float wn[NSCHEMES];
    #pragma unroll
    for (int s = 0; s < NSCHEMES; ++s) wn[s] = aw[s] * scale;

    float acc[NCLS];
    #pragma unroll
    for (int c = 0; c < NCLS; ++c) acc[c] = 0.f;

    #pragma unroll
    for (int mm = 0; mm < 10; ++mm) {
        int s = mm >> 1;
        int k = ((mm & 1) << 3) + L;
        int id = nei[((size_t)s * N + n) * KNEI + k];   // lanes coalesced (32 B/node-group)
        const float4* pp = (const float4*)(probs + (size_t)id * NCLS);
        float4 p0 = pp[0], p1 = pp[1];
        float w = wn[s];
        acc[0] = fmaf(w, p0.x, acc[0]);
        acc[1] = fmaf(w, p0.y, acc[1]);
        acc[2] = fmaf(w, p0.z, acc[2]);
        acc[3] = fmaf(w, p0.w, acc[3]);
        acc[4] = fmaf(w, p1.x, acc[4]);
        acc[5] = fmaf(w, p1.y, acc[5]);
        acc[6] = fmaf(w, p1.z, acc[6]);
        acc[7] = fmaf(w, p1.w, acc[7]);
    }

    // butterfly across the 8-lane node group
    #pragma unroll
    for (int c = 0; c < NCLS; ++c) {
        float v = acc[c];
        v += __shfl_xor(v, 1, 64);
        v += __shfl_xor(v, 2, 64);
        v += __shfl_xor(v, 4, 64);
        acc[c] = v;
    }

    float self = probs[(size_t)n * NCLS + L];
    float res = acc[0];
    #pragma unroll
    for (int c = 1; c < NCLS; ++c) res = (L == c) ? acc[c] : res;
    out[t] = fmaf(g, self, res);
}

extern "C" void kernel_launch(void* const* d_in, const int* in_sizes, int n_in,
                              void* d_out, int out_size, void* d_ws, size_t ws_size,
                              hipStream_t stream) {
    const int*   sc_nei    = (const int*)d_in[0];
    const float* feats     = (const float*)d_in[1];
    const float* W1        = (const float*)d_in[2];
    const float* b1        = (const float*)d_in[3];
    const float* W2        = (const float*)d_in[4];
    const float* b2        = (const float*)d_in[5];
    const float* alpha     = (const float*)d_in[6];
    const float* attention = (const float*)d_in[7];
    float* out = (float*)d_out;

    int N = in_sizes[1] / HIDDEN;  // 50000 nodes

    float* probs = (float*)d_ws;   // N*8 floats = 1.6 MB

    mlp_probs<<<(N + MT - 1) / MT, 256, 0, stream>>>(feats, W1, b1, W2, b2, probs, N);
    combine<<<((N * NCLS) + 255) / 256, 256, 0, stream>>>(sc_nei, probs, attention, alpha, out, N);
}

// Round 5
// 132.560 us; speedup vs baseline: 2.1219x; 1.0580x over previous
//
#include <hip/hip_runtime.h>
#include <hip/hip_bf16.h>
#include <math.h>

#define HIDDEN   128
#define NCLS     8
#define NSCHEMES 5
#define KNEI     16

typedef __attribute__((ext_vector_type(8))) short short8;
typedef __attribute__((ext_vector_type(4))) float floatx4;

// pack two fp32 -> bf16x2 (RNE) in one dword
static __device__ inline unsigned pk2(float x, float y) {
    __hip_bfloat162 v = __float22bfloat162_rn(float2{x, y});
    union { __hip_bfloat162 b; unsigned u; } cv; cv.b = v;
    return cv.u;
}

// W1T[j][k] = bf16(W1[k][j]) : B^T layout so B-fragments are one 16 B load.
__global__ __launch_bounds__(256) void convert_w1(
    const float* __restrict__ W1, unsigned short* __restrict__ W1T)
{
    int idx = blockIdx.x * 256 + threadIdx.x;   // 16384 = 64 blocks
    int j = idx & 127, k = idx >> 7;            // coalesced read over j
    unsigned u = __float_as_uint(W1[k * HIDDEN + j]);
    u = (u + 0x7fffu + ((u >> 16) & 1u)) >> 16; // RNE to bf16
    W1T[j * HIDDEN + k] = (unsigned short)u;
}

// One wave = 16 nodes. Layer 1: 8 j-tiles x 4 K-chunks of mfma_f32_16x16x32_bf16
// (A from fp32 feats via cvt_pk_bf16, B from W1T, no LDS). Layer 2 + softmax in
// fp32 VALU straight from the C-layout accumulators (row=quad*4+reg, col=l16).
__global__ __launch_bounds__(256) void mlp_mfma(
    const float* __restrict__ feats, const unsigned short* __restrict__ W1T,
    const float* __restrict__ b1, const float* __restrict__ W2,
    const float* __restrict__ b2, float* __restrict__ probs, int N)
{
    const int lane = threadIdx.x & 63;
    const int wv   = threadIdx.x >> 6;
    const int quad = lane >> 4;
    const int l16  = lane & 15;
    const int nodeBase = blockIdx.x * 64 + wv * 16;

    int myNode = nodeBase + l16;                 // A-fragment row (m = l16)
    if (myNode >= N) myNode = N - 1;             // clamp; stores guarded below

    floatx4 acc[8];
    #pragma unroll
    for (int t = 0; t < 8; ++t) acc[t] = (floatx4){0.f, 0.f, 0.f, 0.f};

    const float* arow = feats + (size_t)myNode * HIDDEN + quad * 8;
    #pragma unroll
    for (int c = 0; c < 4; ++c) {                // K-chunks of 32
        float4 a0 = *(const float4*)(arow + c * 32);
        float4 a1 = *(const float4*)(arow + c * 32 + 4);
        union { short8 s; unsigned u[4]; } af;
        af.u[0] = pk2(a0.x, a0.y);
        af.u[1] = pk2(a0.z, a0.w);
        af.u[2] = pk2(a1.x, a1.y);
        af.u[3] = pk2(a1.z, a1.w);
        #pragma unroll
        for (int t = 0; t < 8; ++t) {            // j-tiles of 16
            short8 bf = *(const short8*)(W1T + (size_t)(t * 16 + l16) * HIDDEN
                                               + c * 32 + quad * 8);
            acc[t] = __builtin_amdgcn_mfma_f32_16x16x32_bf16(af.s, bf, acc[t], 0, 0, 0);
        }
    }

    // ---- layer 2 (fp32): lane holds h[node = quad*4+r][j = t*16+l16]
    float opart[4][NCLS];
    #pragma unroll
    for (int r = 0; r < 4; ++r)
        #pragma unroll
        for (int c = 0; c < NCLS; ++c) opart[r][c] = 0.f;

    #pragma unroll
    for (int t = 0; t < 8; ++t) {
        int j = t * 16 + l16;
        float bj = b1[j];
        float4 w0 = *(const float4*)(W2 + j * NCLS);
        float4 w1 = *(const float4*)(W2 + j * NCLS + 4);
        #pragma unroll
        for (int r = 0; r < 4; ++r) {
            float h = fmaxf(acc[t][r] + bj, 0.f);
            opart[r][0] = fmaf(h, w0.x, opart[r][0]);
            opart[r][1] = fmaf(h, w0.y, opart[r][1]);
            opart[r][2] = fmaf(h, w0.z, opart[r][2]);
            opart[r][3] = fmaf(h, w0.w, opart[r][3]);
            opart[r][4] = fmaf(h, w1.x, opart[r][4]);
            opart[r][5] = fmaf(h, w1.y, opart[r][5]);
            opart[r][6] = fmaf(h, w1.z, opart[r][6]);
            opart[r][7] = fmaf(h, w1.w, opart[r][7]);
        }
    }

    // reduce over the 16 j-lanes (butterfly stays inside the 16-lane group)
    #pragma unroll
    for (int r = 0; r < 4; ++r)
        #pragma unroll
        for (int c = 0; c < NCLS; ++c) {
            float v = opart[r][c];
            v += __shfl_xor(v, 1, 64);
            v += __shfl_xor(v, 2, 64);
            v += __shfl_xor(v, 4, 64);
            v += __shfl_xor(v, 8, 64);
            opart[r][c] = v;
        }

    if (l16 == 0) {   // one lane per quad finalizes its 4 nodes
        float4 b2lo = *(const float4*)b2;
        float4 b2hi = *(const float4*)(b2 + 4);
        float bb[NCLS] = {b2lo.x, b2lo.y, b2lo.z, b2lo.w, b2hi.x, b2hi.y, b2hi.z, b2hi.w};
        #pragma unroll
        for (int r = 0; r < 4; ++r) {
            int n = nodeBase + quad * 4 + r;
            if (n < N) {
                float o[NCLS];
                #pragma unroll
                for (int c = 0; c < NCLS; ++c) o[c] = opart[r][c] + bb[c];
                float m = o[0];
                #pragma unroll
                for (int c = 1; c < NCLS; ++c) m = fmaxf(m, o[c]);
                float s = 0.f;
                #pragma unroll
                for (int c = 0; c < NCLS; ++c) { o[c] = __expf(o[c] - m); s += o[c]; }
                float inv = 1.f / s;
                float4* op = (float4*)(probs + (size_t)n * NCLS);
                op[0] = make_float4(o[0] * inv, o[1] * inv, o[2] * inv, o[3] * inv);
                op[1] = make_float4(o[4] * inv, o[5] * inv, o[6] * inv, o[7] * inv);
            }
        }
    }
}

// 8 lanes per node. Lane L owns neighbor rows (s, k) for k in {L, L+8}:
// 10 rows, each loaded as two float4 (full 8-class vector), weighted register
// accumulation, 3-step shfl_xor butterfly; lane L emits class L.
__global__ __launch_bounds__(256) void combine(
    const int* __restrict__ nei, const float* __restrict__ probs,
    const float* __restrict__ attention, const float* __restrict__ alpha,
    float* __restrict__ out, int N)
{
    int t = blockIdx.x * 256 + threadIdx.x;
    int n = t >> 3;
    int L = t & 7;
    if (n >= N) return;

    float aw[NSCHEMES];
    float m = -1e30f;
    #pragma unroll
    for (int s = 0; s < NSCHEMES; ++s) {
        aw[s] = attention[(size_t)n * NSCHEMES + s];
        m = fmaxf(m, aw[s]);
    }
    float ssum = 0.f;
    #pragma unroll
    for (int s = 0; s < NSCHEMES; ++s) { aw[s] = __expf(aw[s] - m); ssum += aw[s]; }

    float g = 1.f / (1.f + __expf(-alpha[n]));
    float scale = (1.f - g) / (ssum * (float)KNEI);
    float wn[NSCHEMES];
    #pragma unroll
    for (int s = 0; s < NSCHEMES; ++s) wn[s] = aw[s] * scale;

    float acc[NCLS];
    #pragma unroll
    for (int c = 0; c < NCLS; ++c) acc[c] = 0.f;

    #pragma unroll
    for (int mm = 0; mm < 10; ++mm) {
        int s = mm >> 1;
        int k = ((mm & 1) << 3) + L;
        int id = nei[((size_t)s * N + n) * KNEI + k];
        const float4* pp = (const float4*)(probs + (size_t)id * NCLS);
        float4 p0 = pp[0], p1 = pp[1];
        float w = wn[s];
        acc[0] = fmaf(w, p0.x, acc[0]);
        acc[1] = fmaf(w, p0.y, acc[1]);
        acc[2] = fmaf(w, p0.z, acc[2]);
        acc[3] = fmaf(w, p0.w, acc[3]);
        acc[4] = fmaf(w, p1.x, acc[4]);
        acc[5] = fmaf(w, p1.y, acc[5]);
        acc[6] = fmaf(w, p1.z, acc[6]);
        acc[7] = fmaf(w, p1.w, acc[7]);
    }

    #pragma unroll
    for (int c = 0; c < NCLS; ++c) {
        float v = acc[c];
        v += __shfl_xor(v, 1, 64);
        v += __shfl_xor(v, 2, 64);
        v += __shfl_xor(v, 4, 64);
        acc[c] = v;
    }

    float self = probs[(size_t)n * NCLS + L];
    float res = acc[0];
    #pragma unroll
    for (int c = 1; c < NCLS; ++c) res = (L == c) ? acc[c] : res;
    out[t] = fmaf(g, self, res);
}

extern "C" void kernel_launch(void* const* d_in, const int* in_sizes, int n_in,
                              void* d_out, int out_size, void* d_ws, size_t ws_size,
                              hipStream_t stream) {
    const int*   sc_nei    = (const int*)d_in[0];
    const float* feats     = (const float*)d_in[1];
    const float* W1        = (const float*)d_in[2];
    const float* b1        = (const float*)d_in[3];
    const float* W2        = (const float*)d_in[4];
    const float* b2        = (const float*)d_in[5];
    const float* alpha     = (const float*)d_in[6];
    const float* attention = (const float*)d_in[7];
    float* out = (float*)d_out;

    int N = in_sizes[1] / HIDDEN;  // 50000 nodes

    float* probs = (float*)d_ws;                                  // N*8 fp32 = 1.6 MB
    unsigned short* W1T = (unsigned short*)((float*)d_ws + (size_t)N * NCLS);  // 32 KB, 16B-aligned

    convert_w1<<<(HIDDEN * HIDDEN) / 256, 256, 0, stream>>>(W1, W1T);
    mlp_mfma<<<(N + 63) / 64, 256, 0, stream>>>(feats, W1T, b1, W2, b2, probs, N);
    combine<<<((N * NCLS) + 255) / 256, 256, 0, stream>>>(sc_nei, probs, attention, alpha, out, N);
}

// Round 6
// 121.785 us; speedup vs baseline: 2.3097x; 1.0885x over previous
//
#include <hip/hip_runtime.h>
#include <hip/hip_bf16.h>
#include <math.h>

#define HIDDEN   128
#define NCLS     8
#define NSCHEMES 5
#define KNEI     16
#define NFRAG    2048   // 8 t-tiles * 4 k-chunks * 64 lanes

typedef __attribute__((ext_vector_type(8))) short short8;
typedef __attribute__((ext_vector_type(4))) float floatx4;

// pack two fp32 -> bf16x2 (RNE) in one dword
static __device__ inline unsigned pk2(float x, float y) {
    __hip_bfloat162 v = __float22bfloat162_rn(float2{x, y});
    union { __hip_bfloat162 b; unsigned u; } cv; cv.b = v;
    return cv.u;
}
static __device__ inline float bf2f(unsigned short u) {
    return __uint_as_float(((unsigned)u) << 16);
}

// Emit W1 as bf16 MFMA B-fragments in fragment order:
//   frag f = t*256 + c*64 + lane ; lane = quad*16 + l16
//   frag[f][i] = bf16( W1[c*32 + quad*8 + i][t*16 + l16] ),  i = 0..7  (16 B)
// so mlp staging is a single coalesced contiguous stream.
__global__ __launch_bounds__(256) void convert_w1(
    const float* __restrict__ W1, unsigned short* __restrict__ W1frag)
{
    int f = blockIdx.x * 256 + threadIdx.x;   // 8 blocks x 256 = 2048
    int lane = f & 63, c = (f >> 6) & 3, t = f >> 8;
    int q = lane >> 4, l16 = lane & 15;
    int j  = t * 16 + l16;
    int k0 = c * 32 + q * 8;
    union { short8 s; unsigned u[4]; } r;
    #pragma unroll
    for (int p = 0; p < 4; ++p) {
        float a = W1[(size_t)(k0 + 2 * p)     * HIDDEN + j];
        float b = W1[(size_t)(k0 + 2 * p + 1) * HIDDEN + j];
        r.u[p] = pk2(a, b);
    }
    *(short8*)(W1frag + (size_t)f * 8) = r.s;
}

// One wave = 16 nodes, block = 64 nodes. W1 fragments live in LDS (staged
// coalesced once per block, shared by all 4 waves); feats are the only HBM
// stream. Layer 2 + softmax in fp32 from the C-layout accumulators
// (row = quad*4+reg, col = l16); probs written as bf16 rows (16 B).
__global__ __launch_bounds__(256, 4) void mlp_mfma(
    const float* __restrict__ feats, const unsigned short* __restrict__ W1frag,
    const float* __restrict__ b1, const float* __restrict__ W2,
    const float* __restrict__ b2, unsigned short* __restrict__ probsb, int N)
{
    __shared__ unsigned short fragLds[NFRAG * 8];   // 32 KB
    __shared__ float W2l[HIDDEN * NCLS];            // 4 KB
    __shared__ float b1l[HIDDEN];

    const int tid  = threadIdx.x;
    const int lane = tid & 63;
    const int wv   = tid >> 6;
    const int quad = lane >> 4;
    const int l16  = lane & 15;
    const int nodeBase = blockIdx.x * 64 + wv * 16;

    // ---- stage: W1 fragments (contiguous, coalesced), W2, b1
    #pragma unroll
    for (int it = 0; it < 8; ++it) {
        short8 v = *(const short8*)(W1frag + (size_t)(it * 256 + tid) * 8);
        *(short8*)&fragLds[(it * 256 + tid) * 8] = v;
    }
    {
        float4 v = ((const float4*)W2)[tid];        // 256 float4 == whole W2
        *(float4*)&W2l[4 * tid] = v;
    }
    if (tid < HIDDEN) b1l[tid] = b1[tid];
    __syncthreads();

    int myNode = nodeBase + l16;
    if (myNode >= N) myNode = N - 1;

    floatx4 acc[8];
    #pragma unroll
    for (int t = 0; t < 8; ++t) acc[t] = (floatx4){0.f, 0.f, 0.f, 0.f};

    const float* arow = feats + (size_t)myNode * HIDDEN + quad * 8;
    #pragma unroll
    for (int c = 0; c < 4; ++c) {                   // K-chunks of 32
        float4 a0 = *(const float4*)(arow + c * 32);
        float4 a1 = *(const float4*)(arow + c * 32 + 4);
        union { short8 s; unsigned u[4]; } af;
        af.u[0] = pk2(a0.x, a0.y);
        af.u[1] = pk2(a0.z, a0.w);
        af.u[2] = pk2(a1.x, a1.y);
        af.u[3] = pk2(a1.z, a1.w);
        #pragma unroll
        for (int t = 0; t < 8; ++t) {               // j-tiles of 16
            short8 bf = *(const short8*)&fragLds[((t * 4 + c) * 64 + lane) * 8];
            acc[t] = __builtin_amdgcn_mfma_f32_16x16x32_bf16(af.s, bf, acc[t], 0, 0, 0);
        }
    }

    // ---- layer 2 (fp32): lane holds h[node = quad*4+r][j = t*16+l16]
    float opart[4][NCLS];
    #pragma unroll
    for (int r = 0; r < 4; ++r)
        #pragma unroll
        for (int c = 0; c < NCLS; ++c) opart[r][c] = 0.f;

    #pragma unroll
    for (int t = 0; t < 8; ++t) {
        int j = t * 16 + l16;
        float bj = b1l[j];
        float4 w0 = *(const float4*)&W2l[j * NCLS];
        float4 w1 = *(const float4*)&W2l[j * NCLS + 4];
        #pragma unroll
        for (int r = 0; r < 4; ++r) {
            float h = fmaxf(acc[t][r] + bj, 0.f);
            opart[r][0] = fmaf(h, w0.x, opart[r][0]);
            opart[r][1] = fmaf(h, w0.y, opart[r][1]);
            opart[r][2] = fmaf(h, w0.z, opart[r][2]);
            opart[r][3] = fmaf(h, w0.w, opart[r][3]);
            opart[r][4] = fmaf(h, w1.x, opart[r][4]);
            opart[r][5] = fmaf(h, w1.y, opart[r][5]);
            opart[r][6] = fmaf(h, w1.z, opart[r][6]);
            opart[r][7] = fmaf(h, w1.w, opart[r][7]);
        }
    }

    // reduce over the 16 j-lanes (butterfly stays in the 16-lane group)
    #pragma unroll
    for (int r = 0; r < 4; ++r)
        #pragma unroll
        for (int c = 0; c < NCLS; ++c) {
            float v = opart[r][c];
            v += __shfl_xor(v, 1, 64);
            v += __shfl_xor(v, 2, 64);
            v += __shfl_xor(v, 4, 64);
            v += __shfl_xor(v, 8, 64);
            opart[r][c] = v;
        }

    if (l16 == 0) {   // one lane per quad finalizes its 4 nodes
        float4 b2lo = *(const float4*)b2;
        float4 b2hi = *(const float4*)(b2 + 4);
        float bb[NCLS] = {b2lo.x, b2lo.y, b2lo.z, b2lo.w, b2hi.x, b2hi.y, b2hi.z, b2hi.w};
        #pragma unroll
        for (int r = 0; r < 4; ++r) {
            int n = nodeBase + quad * 4 + r;
            if (n < N) {
                float o[NCLS];
                #pragma unroll
                for (int c = 0; c < NCLS; ++c) o[c] = opart[r][c] + bb[c];
                float m = o[0];
                #pragma unroll
                for (int c = 1; c < NCLS; ++c) m = fmaxf(m, o[c]);
                float s = 0.f;
                #pragma unroll
                for (int c = 0; c < NCLS; ++c) { o[c] = __expf(o[c] - m); s += o[c]; }
                float inv = 1.f / s;
                union { short8 s8; unsigned u[4]; } pr;
                pr.u[0] = pk2(o[0] * inv, o[1] * inv);
                pr.u[1] = pk2(o[2] * inv, o[3] * inv);
                pr.u[2] = pk2(o[4] * inv, o[5] * inv);
                pr.u[3] = pk2(o[6] * inv, o[7] * inv);
                *(short8*)(probsb + (size_t)n * NCLS) = pr.s8;
            }
        }
    }
}

// 8 lanes per node. Lane L owns neighbor rows (s, k) for k in {L, L+8}:
// 10 rows, each a single 16 B bf16x8 gather (full class vector), weighted
// register accumulation, 3-step shfl_xor butterfly; lane L emits class L.
__global__ __launch_bounds__(256) void combine(
    const int* __restrict__ nei, const unsigned short* __restrict__ probsb,
    const float* __restrict__ attention, const float* __restrict__ alpha,
    float* __restrict__ out, int N)
{
    int t = blockIdx.x * 256 + threadIdx.x;
    int n = t >> 3;
    int L = t & 7;
    if (n >= N) return;

    float aw[NSCHEMES];
    float m = -1e30f;
    #pragma unroll
    for (int s = 0; s < NSCHEMES; ++s) {
        aw[s] = attention[(size_t)n * NSCHEMES + s];
        m = fmaxf(m, aw[s]);
    }
    float ssum = 0.f;
    #pragma unroll
    for (int s = 0; s < NSCHEMES; ++s) { aw[s] = __expf(aw[s] - m); ssum += aw[s]; }

    float g = 1.f / (1.f + __expf(-alpha[n]));
    float scale = (1.f - g) / (ssum * (float)KNEI);
    float wn[NSCHEMES];
    #pragma unroll
    for (int s = 0; s < NSCHEMES; ++s) wn[s] = aw[s] * scale;

    float acc[NCLS];
    #pragma unroll
    for (int c = 0; c < NCLS; ++c) acc[c] = 0.f;

    #pragma unroll
    for (int mm = 0; mm < 10; ++mm) {
        int s = mm >> 1;
        int k = ((mm & 1) << 3) + L;
        int id = nei[((size_t)s * N + n) * KNEI + k];   // coalesced
        short8 pr = *(const short8*)(probsb + (size_t)id * NCLS);  // one 16 B gather
        float w = wn[s];
        #pragma unroll
        for (int c = 0; c < NCLS; ++c)
            acc[c] = fmaf(w, bf2f((unsigned short)pr[c]), acc[c]);
    }

    #pragma unroll
    for (int c = 0; c < NCLS; ++c) {
        float v = acc[c];
        v += __shfl_xor(v, 1, 64);
        v += __shfl_xor(v, 2, 64);
        v += __shfl_xor(v, 4, 64);
        acc[c] = v;
    }

    float self = bf2f(probsb[(size_t)n * NCLS + L]);
    float res = acc[0];
    #pragma unroll
    for (int c = 1; c < NCLS; ++c) res = (L == c) ? acc[c] : res;
    out[t] = fmaf(g, self, res);
}

extern "C" void kernel_launch(void* const* d_in, const int* in_sizes, int n_in,
                              void* d_out, int out_size, void* d_ws, size_t ws_size,
                              hipStream_t stream) {
    const int*   sc_nei    = (const int*)d_in[0];
    const float* feats     = (const float*)d_in[1];
    const float* W1        = (const float*)d_in[2];
    const float* b1        = (const float*)d_in[3];
    const float* W2        = (const float*)d_in[4];
    const float* b2        = (const float*)d_in[5];
    const float* alpha     = (const float*)d_in[6];
    const float* attention = (const float*)d_in[7];
    float* out = (float*)d_out;

    int N = in_sizes[1] / HIDDEN;  // 50000 nodes

    unsigned short* probsb = (unsigned short*)d_ws;                 // N*8 bf16 = 800 KB
    unsigned short* W1frag = (unsigned short*)d_ws + (size_t)N * NCLS;  // 32 KB, 16 B aligned

    convert_w1<<<NFRAG / 256, 256, 0, stream>>>(W1, W1frag);
    mlp_mfma<<<(N + 63) / 64, 256, 0, stream>>>(feats, W1frag, b1, W2, b2, probsb, N);
    combine<<<((N * NCLS) + 255) / 256, 256, 0, stream>>>(sc_nei, probsb, attention, alpha, out, N);
}

// Round 7
// 120.824 us; speedup vs baseline: 2.3280x; 1.0079x over previous
//
#include <hip/hip_runtime.h>
#include <hip/hip_bf16.h>
#include <hip/hip_fp16.h>
#include <math.h>

#define HIDDEN   128
#define NCLS     8
#define NSCHEMES 5
#define KNEI     16
#define NFRAG    2048   // 8 t-tiles * 4 k-chunks * 64 lanes

typedef __attribute__((ext_vector_type(8))) short short8;
typedef __attribute__((ext_vector_type(4))) float floatx4;

// pack two fp32 -> bf16x2 (RNE) in one dword
static __device__ inline unsigned pk2(float x, float y) {
    __hip_bfloat162 v = __float22bfloat162_rn(float2{x, y});
    union { __hip_bfloat162 b; unsigned u; } cv; cv.b = v;
    return cv.u;
}
// pack two fp32 -> fp16x2 (RNE) in one dword
static __device__ inline unsigned pkh2(float x, float y) {
    __half2 v = __floats2half2_rn(x, y);
    union { __half2 h; unsigned u; } cv; cv.h = v;
    return cv.u;
}

// Emit W1 as bf16 MFMA B-fragments in fragment order:
//   frag f = t*256 + c*64 + lane ; lane = quad*16 + l16
//   frag[f][i] = bf16( W1[c*32 + quad*8 + i][t*16 + l16] ),  i = 0..7  (16 B)
__global__ __launch_bounds__(256) void convert_w1(
    const float* __restrict__ W1, unsigned short* __restrict__ W1frag)
{
    int f = blockIdx.x * 256 + threadIdx.x;   // 8 blocks x 256 = 2048
    int lane = f & 63, c = (f >> 6) & 3, t = f >> 8;
    int q = lane >> 4, l16 = lane & 15;
    int j  = t * 16 + l16;
    int k0 = c * 32 + q * 8;
    union { short8 s; unsigned u[4]; } r;
    #pragma unroll
    for (int p = 0; p < 4; ++p) {
        float a = W1[(size_t)(k0 + 2 * p)     * HIDDEN + j];
        float b = W1[(size_t)(k0 + 2 * p + 1) * HIDDEN + j];
        r.u[p] = pk2(a, b);
    }
    *(short8*)(W1frag + (size_t)f * 8) = r.s;
}

// One wave = 16 nodes, block = 64 nodes. W1 fragments live in LDS (staged
// coalesced once per block, shared by all 4 waves); feats are the only HBM
// stream. Layer 2 + softmax in fp32 from the C-layout accumulators
// (row = quad*4+reg, col = l16); probs written as fp16 rows (16 B).
__global__ __launch_bounds__(256, 4) void mlp_mfma(
    const float* __restrict__ feats, const unsigned short* __restrict__ W1frag,
    const float* __restrict__ b1, const float* __restrict__ W2,
    const float* __restrict__ b2, unsigned short* __restrict__ probsh, int N)
{
    __shared__ unsigned short fragLds[NFRAG * 8];   // 32 KB
    __shared__ float W2l[HIDDEN * NCLS];            // 4 KB
    __shared__ float b1l[HIDDEN];

    const int tid  = threadIdx.x;
    const int lane = tid & 63;
    const int wv   = tid >> 6;
    const int quad = lane >> 4;
    const int l16  = lane & 15;
    const int nodeBase = blockIdx.x * 64 + wv * 16;

    #pragma unroll
    for (int it = 0; it < 8; ++it) {
        short8 v = *(const short8*)(W1frag + (size_t)(it * 256 + tid) * 8);
        *(short8*)&fragLds[(it * 256 + tid) * 8] = v;
    }
    {
        float4 v = ((const float4*)W2)[tid];        // 256 float4 == whole W2
        *(float4*)&W2l[4 * tid] = v;
    }
    if (tid < HIDDEN) b1l[tid] = b1[tid];
    __syncthreads();

    int myNode = nodeBase + l16;
    if (myNode >= N) myNode = N - 1;

    floatx4 acc[8];
    #pragma unroll
    for (int t = 0; t < 8; ++t) acc[t] = (floatx4){0.f, 0.f, 0.f, 0.f};

    const float* arow = feats + (size_t)myNode * HIDDEN + quad * 8;
    #pragma unroll
    for (int c = 0; c < 4; ++c) {                   // K-chunks of 32
        float4 a0 = *(const float4*)(arow + c * 32);
        float4 a1 = *(const float4*)(arow + c * 32 + 4);
        union { short8 s; unsigned u[4]; } af;
        af.u[0] = pk2(a0.x, a0.y);
        af.u[1] = pk2(a0.z, a0.w);
        af.u[2] = pk2(a1.x, a1.y);
        af.u[3] = pk2(a1.z, a1.w);
        #pragma unroll
        for (int t = 0; t < 8; ++t) {               // j-tiles of 16
            short8 bf = *(const short8*)&fragLds[((t * 4 + c) * 64 + lane) * 8];
            acc[t] = __builtin_amdgcn_mfma_f32_16x16x32_bf16(af.s, bf, acc[t], 0, 0, 0);
        }
    }

    // ---- layer 2 (fp32): lane holds h[node = quad*4+r][j = t*16+l16]
    float opart[4][NCLS];
    #pragma unroll
    for (int r = 0; r < 4; ++r)
        #pragma unroll
        for (int c = 0; c < NCLS; ++c) opart[r][c] = 0.f;

    #pragma unroll
    for (int t = 0; t < 8; ++t) {
        int j = t * 16 + l16;
        float bj = b1l[j];
        float4 w0 = *(const float4*)&W2l[j * NCLS];
        float4 w1 = *(const float4*)&W2l[j * NCLS + 4];
        #pragma unroll
        for (int r = 0; r < 4; ++r) {
            float h = fmaxf(acc[t][r] + bj, 0.f);
            opart[r][0] = fmaf(h, w0.x, opart[r][0]);
            opart[r][1] = fmaf(h, w0.y, opart[r][1]);
            opart[r][2] = fmaf(h, w0.z, opart[r][2]);
            opart[r][3] = fmaf(h, w0.w, opart[r][3]);
            opart[r][4] = fmaf(h, w1.x, opart[r][4]);
            opart[r][5] = fmaf(h, w1.y, opart[r][5]);
            opart[r][6] = fmaf(h, w1.z, opart[r][6]);
            opart[r][7] = fmaf(h, w1.w, opart[r][7]);
        }
    }

    // reduce over the 16 j-lanes (butterfly stays in the 16-lane group)
    #pragma unroll
    for (int r = 0; r < 4; ++r)
        #pragma unroll
        for (int c = 0; c < NCLS; ++c) {
            float v = opart[r][c];
            v += __shfl_xor(v, 1, 64);
            v += __shfl_xor(v, 2, 64);
            v += __shfl_xor(v, 4, 64);
            v += __shfl_xor(v, 8, 64);
            opart[r][c] = v;
        }

    if (l16 == 0) {   // one lane per quad finalizes its 4 nodes
        float4 b2lo = *(const float4*)b2;
        float4 b2hi = *(const float4*)(b2 + 4);
        float bb[NCLS] = {b2lo.x, b2lo.y, b2lo.z, b2lo.w, b2hi.x, b2hi.y, b2hi.z, b2hi.w};
        #pragma unroll
        for (int r = 0; r < 4; ++r) {
            int n = nodeBase + quad * 4 + r;
            if (n < N) {
                float o[NCLS];
                #pragma unroll
                for (int c = 0; c < NCLS; ++c) o[c] = opart[r][c] + bb[c];
                float m = o[0];
                #pragma unroll
                for (int c = 1; c < NCLS; ++c) m = fmaxf(m, o[c]);
                float s = 0.f;
                #pragma unroll
                for (int c = 0; c < NCLS; ++c) { o[c] = __expf(o[c] - m); s += o[c]; }
                float inv = 1.f / s;
                union { short8 s8; unsigned u[4]; } pr;
                pr.u[0] = pkh2(o[0] * inv, o[1] * inv);
                pr.u[1] = pkh2(o[2] * inv, o[3] * inv);
                pr.u[2] = pkh2(o[4] * inv, o[5] * inv);
                pr.u[3] = pkh2(o[6] * inv, o[7] * inv);
                *(short8*)(probsh + (size_t)n * NCLS) = pr.s8;
            }
        }
    }
}

// 16 lanes per node: u = (kh<<3)|L. Thread handles neighbor k = kh*8+L for all
// 5 schemes: phase A = 5 independent idx loads, phase B = 5 independent 16 B
// fp16-row gathers (only 2 exposed latencies). 4-step shfl_xor butterfly over
// the 16-lane group; lanes u<8 emit class u.
__global__ __launch_bounds__(256) void combine(
    const int* __restrict__ nei, const unsigned short* __restrict__ probsh,
    const float* __restrict__ attention, const float* __restrict__ alpha,
    float* __restrict__ out, int N)
{
    int t = blockIdx.x * 256 + threadIdx.x;
    int n = t >> 4;
    int u = t & 15;
    int k = u;                 // kh*8 + L  (u directly spans k = 0..15)
    int L = u & 7;
    if (n >= N) return;

    // attention softmax over 5 schemes (redundant across the 16 lanes)
    float aw[NSCHEMES];
    float m = -1e30f;
    #pragma unroll
    for (int s = 0; s < NSCHEMES; ++s) {
        aw[s] = attention[(size_t)n * NSCHEMES + s];
        m = fmaxf(m, aw[s]);
    }
    float ssum = 0.f;
    #pragma unroll
    for (int s = 0; s < NSCHEMES; ++s) { aw[s] = __expf(aw[s] - m); ssum += aw[s]; }

    float g = 1.f / (1.f + __expf(-alpha[n]));
    float scale = (1.f - g) / (ssum * (float)KNEI);
    float wn[NSCHEMES];
    #pragma unroll
    for (int s = 0; s < NSCHEMES; ++s) wn[s] = aw[s] * scale;

    // phase A: all 5 neighbor indices in flight (16 lanes cover one 64 B row)
    int id[NSCHEMES];
    #pragma unroll
    for (int s = 0; s < NSCHEMES; ++s)
        id[s] = nei[((size_t)s * N + n) * KNEI + k];

    // self prob (independent; issued alongside)
    float self;
    {
        union { unsigned u32; __half h[2]; } cv;
        cv.u32 = *(const unsigned short*)&probsh[(size_t)n * NCLS + L] |
                 ((unsigned)probsh[(size_t)n * NCLS + L] << 16);
        self = __half2float(cv.h[0]);
    }

    // phase B: all 5 gathers in flight
    float acc[NCLS];
    #pragma unroll
    for (int c = 0; c < NCLS; ++c) acc[c] = 0.f;
    #pragma unroll
    for (int s = 0; s < NSCHEMES; ++s) {
        union { uint4 v; __half h[8]; } pr;
        pr.v = *(const uint4*)(probsh + (size_t)id[s] * NCLS);
        float w = wn[s];
        #pragma unroll
        for (int c = 0; c < NCLS; ++c)
            acc[c] = fmaf(w, __half2float(pr.h[c]), acc[c]);
    }

    // butterfly over the 16-lane node group
    #pragma unroll
    for (int c = 0; c < NCLS; ++c) {
        float v = acc[c];
        v += __shfl_xor(v, 1, 64);
        v += __shfl_xor(v, 2, 64);
        v += __shfl_xor(v, 4, 64);
        v += __shfl_xor(v, 8, 64);
        acc[c] = v;
    }

    if (u < 8) {
        float res = acc[0];
        #pragma unroll
        for (int c = 1; c < NCLS; ++c) res = (u == c) ? acc[c] : res;
        out[(size_t)n * NCLS + u] = fmaf(g, self, res);
    }
}

extern "C" void kernel_launch(void* const* d_in, const int* in_sizes, int n_in,
                              void* d_out, int out_size, void* d_ws, size_t ws_size,
                              hipStream_t stream) {
    const int*   sc_nei    = (const int*)d_in[0];
    const float* feats     = (const float*)d_in[1];
    const float* W1        = (const float*)d_in[2];
    const float* b1        = (const float*)d_in[3];
    const float* W2        = (const float*)d_in[4];
    const float* b2        = (const float*)d_in[5];
    const float* alpha     = (const float*)d_in[6];
    const float* attention = (const float*)d_in[7];
    float* out = (float*)d_out;

    int N = in_sizes[1] / HIDDEN;  // 50000 nodes

    unsigned short* probsh = (unsigned short*)d_ws;                    // N*8 fp16 = 800 KB
    unsigned short* W1frag = (unsigned short*)d_ws + (size_t)N * NCLS; // 32 KB, 16 B aligned

    convert_w1<<<NFRAG / 256, 256, 0, stream>>>(W1, W1frag);
    mlp_mfma<<<(N + 63) / 64, 256, 0, stream>>>(feats, W1frag, b1, W2, b2, probsh, N);
    combine<<<((N * 16) + 255) / 256, 256, 0, stream>>>(sc_nei, probsh, attention, alpha, out, N);
}